// Round 6
// baseline (1286.054 us; speedup 1.0000x reference)
//
#include <hip/hip_runtime.h>

typedef float v2f __attribute__((ext_vector_type(2)));
typedef float v4f __attribute__((ext_vector_type(4)));
typedef unsigned long long u64;

#define HID 30
#define TSTEPS 2048
#define BATCH 512
#define L2E 1.4426950408889634f
#define RSLOT 64    // ring depth in steps
#define CHUNK 16    // flag granularity in steps

__device__ __forceinline__ float fexp2(float x) { return __builtin_amdgcn_exp2f(x); }
__device__ __forceinline__ float frcp(float x)  { return __builtin_amdgcn_rcpf(x); }
__device__ __forceinline__ void  pinf(float& v) { asm("" : "+v"(v)); }
__device__ __forceinline__ void  pinf2(v2f& v)  { asm("" : "+v"(v)); }

__device__ __forceinline__ u64 pk2(int lo, int hi) {
    return ((u64)(unsigned)hi << 32) | (unsigned)lo;
}

// TWO BATCH ELEMENTS PER WAVE: accumulators are {b0, b1} pairs, weights stay
// {rowA, rowB} pairs. op_sel broadcasts ONE weight half to both result halves
// while the h operand {h_b0, h_b1} maps straight through.
//   WA: acc{b0,b1} += w.x * h{b0,b1}    (rowA weight)
//   WB: acc{b0,b1} += w.y * h{b0,b1}    (rowB weight)
// (derived from the R2/R4/R5-proven LO/HI macros: op_sel = lo-half selectors,
//  op_sel_hi = hi-half selectors, bit order [S0,S1,S2])
#define PKFMA_WA(acc, w, s64)                                                \
    asm("v_pk_fma_f32 %0, %1, %2, %0 op_sel:[0,0,0] op_sel_hi:[0,1,1]"       \
        : "+v"(acc) : "v"(w), "s"(s64))
#define PKFMA_WB(acc, w, s64)                                                \
    asm("v_pk_fma_f32 %0, %1, %2, %0 op_sel:[1,0,0] op_sel_hi:[1,1,1]"       \
        : "+v"(acc) : "v"(w), "s"(s64))
// VGPR-pair h variants (LDS-loaded {h_b0, h_b1})
#define PKFMA_WAV(acc, w, hv)                                                \
    asm("v_pk_fma_f32 %0, %1, %2, %0 op_sel:[0,0,0] op_sel_hi:[0,1,1]"       \
        : "+v"(acc) : "v"(w), "v"(hv))
#define PKFMA_WBV(acc, w, hv)                                                \
    asm("v_pk_fma_f32 %0, %1, %2, %0 op_sel:[1,0,0] op_sel_hi:[1,1,1]"       \
        : "+v"(acc) : "v"(w), "v"(hv))

// p from the other 32-lane half (lane ^ 32) via gfx950 VALU permlane32_swap.
__device__ __forceinline__ float other_half(float p, int h) {
#if __has_builtin(__builtin_amdgcn_permlane32_swap)
    auto r = __builtin_amdgcn_permlane32_swap(__float_as_uint(p), __float_as_uint(p),
                                              false, false);
    return __uint_as_float(h ? r[0] : r[1]);
#else
    return __shfl_xor(p, 32);
#endif
}

// Wave-wide sum via DPP (VALU pipe). Valid in lane 63.
__device__ __forceinline__ float dpp_reduce63(float x) {
    x += __int_as_float(__builtin_amdgcn_update_dpp(0, __float_as_int(x), 0x111, 0xf, 0xf, true));
    x += __int_as_float(__builtin_amdgcn_update_dpp(0, __float_as_int(x), 0x112, 0xf, 0xf, true));
    x += __int_as_float(__builtin_amdgcn_update_dpp(0, __float_as_int(x), 0x114, 0xf, 0xf, true));
    x += __int_as_float(__builtin_amdgcn_update_dpp(0, __float_as_int(x), 0x118, 0xf, 0xf, true));
    x += __int_as_float(__builtin_amdgcn_update_dpp(0, __float_as_int(x), 0x142, 0xf, 0xf, true));
    x += __int_as_float(__builtin_amdgcn_update_dpp(0, __float_as_int(x), 0x143, 0xf, 0xf, true));
    return x;
}

// DECOUPLED 3-WAVE CHAIN processing TWO batch elements per block.
// R0/R2/R4/R5 all pinned at ~1140 cy/step regardless of structure -> the
// per-step serial chain is the floor. Amortize it: 2 independent LSTM chains
// share each wave's instruction stream (pk ops do both in ONE instruction;
// trans/readlane double but pipeline into the stall gaps). Weight regs
// unchanged at 60/wave (spill-free regime, R5-verified at VGPR=68).
__global__ __launch_bounds__(192, 1)
void lstm2_kernel(const float* __restrict__ x,
                  const float* __restrict__ w_ih1, const float* __restrict__ w_hh1,
                  const float* __restrict__ b_ih1, const float* __restrict__ b_hh1,
                  const float* __restrict__ w_ih2, const float* __restrict__ w_hh2,
                  const float* __restrict__ b_ih2, const float* __restrict__ b_hh2,
                  const float* __restrict__ w_fc,  const float* __restrict__ b_fc,
                  float* __restrict__ out)
{
    const int b0   = blockIdx.x * 2;        // two batch elements per block
    const int b1   = b0 + 1;
    const int tid  = threadIdx.x;
    const int wave = tid >> 6;
    const int lane = tid & 63;
    const int k    = lane & 31;
    const int h    = lane >> 5;
    const int kk   = (k < HID) ? k : (HID - 1);  // lanes k=30,31 duplicate unit 29
    const int rowA = h * 30 + kk;                // h0: i-row, h1: f-row
    const int rowB = 60 + h * 30 + kk;           // h0: g-row, h1: o-row

    __shared__ __align__(16) v2f h1ring[RSLOT][32];  // h1(t) as {b0,b1} (30 used)
    __shared__ __align__(16) v4f pring[RSLOT][64];   // {preA b0,b1, preB b0,b1}
    __shared__ int f01, f12, c10, c21;
    if (tid == 0) { f01 = -1; f12 = -1; c10 = -1; c21 = -1; }
    __syncthreads();                  // only barrier in the kernel

    // gate-y activation constants: h0 -> tanh (g), h1 -> sigmoid (o)
    const float cy = h ? (-L2E) : (-2.0f * L2E);
    const float my = h ? 1.0f : 2.0f;
    const float ay = h ? 0.0f : -1.0f;

    v2f z2; z2.x = 0.0f; z2.y = 0.0f;

    if (wave == 0) {
        // ================= stage 0: layer1 recurrence (2 chains) ============
        v2f w1[30];
#pragma unroll
        for (int j = 0; j < 30; ++j) {
            w1[j].x = w_hh1[rowA * HID + j];  w1[j].y = w_hh1[rowB * HID + j];
        }
        v2f b1A2, b1B2, wx;
        b1A2.x = b1A2.y = b_ih1[rowA] + b_hh1[rowA];
        b1B2.x = b1B2.y = b_ih1[rowB] + b_hh1[rowB];
        wx.x = w_ih1[rowA];  wx.y = w_ih1[rowB];
#pragma unroll
        for (int j = 0; j < 30; ++j) pinf2(w1[j]);
        pinf2(wx);

        v2f c1 = z2, hh = z2;
        v2f aAe = b1A2, aAo = z2, aBe = b1B2, aBo = z2;  // carried b1+W_hh1.h1(t-1)
        const float* xp0 = x + (size_t)b0 * TSTEPS;
        const float* xp1 = x + (size_t)b1 * TSTEPS;
        float xv0c = xp0[lane], xv0n = xp0[64 + lane];
        float xv1c = xp1[lane], xv1n = xp1[64 + lane];

        for (int t = 0; t < TSTEPS; ++t) {
            if ((t & (CHUNK - 1)) == 0 && t >= RSLOT) {
                while (__hip_atomic_load(&c10, __ATOMIC_ACQUIRE,
                                         __HIP_MEMORY_SCOPE_WORKGROUP) < t - (RSLOT - CHUNK + 1))
                    __builtin_amdgcn_s_sleep(1);
            }
            // ---------------- layer 1, step t (both chains) ----------------
            const u64 xt64 = pk2(__builtin_amdgcn_readlane(__float_as_int(xv0c), t & 63),
                                 __builtin_amdgcn_readlane(__float_as_int(xv1c), t & 63));
            v2f preA = aAe + aAo;
            v2f preB = aBe + aBo;
            PKFMA_WA(preA, wx, xt64);   // preA{b0,b1} += wxa * x{b0,b1}
            PKFMA_WB(preB, wx, xt64);   // preB{b0,b1} += wxb * x{b0,b1}
            v2f gx, gy;
            gx.x = frcp(1.0f + fexp2(preA.x * (-L2E)));            // i / f
            gx.y = frcp(1.0f + fexp2(preA.y * (-L2E)));
            gy.x = fmaf(frcp(1.0f + fexp2(preB.x * cy)), my, ay);  // g / o
            gy.y = fmaf(frcp(1.0f + fexp2(preB.y * cy)), my, ay);
            v2f p = gx * gy;
            v2f px;
            px.x = other_half(p.x, h);
            px.y = other_half(p.y, h);
            c1 = gx * c1 + px;
            v2f tc;
            tc.x = fmaf(2.0f, frcp(1.0f + fexp2(c1.x * (-2.0f * L2E))), -1.0f);
            tc.y = fmaf(2.0f, frcp(1.0f + fexp2(c1.y * (-2.0f * L2E))), -1.0f);
            hh = gy * tc;               // h1(t)[kk] for {b0,b1}, valid in h=1
            const int hlo = __float_as_int(hh.x), hhi = __float_as_int(hh.y);

            // ---- broadcast h1(t) -> carried W_hh1 partial for t+1 ----
            aAe = b1A2; aAo = z2; aBe = b1B2; aBo = z2;
#pragma unroll
            for (int j = 0; j < 30; j += 2) {
                const u64 hj  = pk2(__builtin_amdgcn_readlane(hlo, 32 + j),
                                    __builtin_amdgcn_readlane(hhi, 32 + j));
                const u64 hj1 = pk2(__builtin_amdgcn_readlane(hlo, 33 + j),
                                    __builtin_amdgcn_readlane(hhi, 33 + j));
                PKFMA_WA(aAe, w1[j],     hj);
                PKFMA_WB(aBe, w1[j],     hj);
                PKFMA_WA(aAo, w1[j + 1], hj1);
                PKFMA_WB(aBo, w1[j + 1], hj1);
            }

            if (h) h1ring[t & (RSLOT - 1)][kk] = hh;    // publish {b0,b1}
            if ((t & (CHUNK - 1)) == (CHUNK - 1) && lane == 0)
                __hip_atomic_store(&f01, t, __ATOMIC_RELEASE,
                                   __HIP_MEMORY_SCOPE_WORKGROUP);

            if ((t & 63) == 63) {                        // x chunk rotate
                xv0c = xv0n; xv1c = xv1n;
                if (t + 65 < TSTEPS) {
                    xv0n = xp0[t + 65 + lane];
                    xv1n = xp1[t + 65 + lane];
                }
            }
        }
    } else if (wave == 1) {
        // ================= stage 1: W_ih2 * h1 + b2 (2 chains) ==============
        v2f wi2[30];
#pragma unroll
        for (int j = 0; j < 30; ++j) {
            wi2[j].x = w_ih2[rowA * HID + j];  wi2[j].y = w_ih2[rowB * HID + j];
        }
        v2f b2A2, b2B2;
        b2A2.x = b2A2.y = b_ih2[rowA] + b_hh2[rowA];
        b2B2.x = b2B2.y = b_ih2[rowB] + b_hh2[rowB];
#pragma unroll
        for (int j = 0; j < 30; ++j) pinf2(wi2[j]);

        for (int t = 0; t < TSTEPS; ++t) {
            if ((t & (CHUNK - 1)) == 0) {
                if (t >= RSLOT) {   // partial-ring back-pressure
                    while (__hip_atomic_load(&c21, __ATOMIC_ACQUIRE,
                                             __HIP_MEMORY_SCOPE_WORKGROUP) < t - (RSLOT - CHUNK + 1))
                        __builtin_amdgcn_s_sleep(1);
                }
                while (__hip_atomic_load(&f01, __ATOMIC_ACQUIRE,
                                         __HIP_MEMORY_SCOPE_WORKGROUP) < t + CHUNK - 1)
                    __builtin_amdgcn_s_sleep(1);
            }
            // uniform-address LDS broadcast reads of h1(t) {b0,b1} pairs
            const v2f* rd = h1ring[t & (RSLOT - 1)];
            v2f iAe = b2A2, iAo = z2, iBe = b2B2, iBo = z2;
#pragma unroll
            for (int j = 0; j < 30; j += 2) {
                const v2f h0p = rd[j];
                const v2f h1p = rd[j + 1];
                PKFMA_WAV(iAe, wi2[j],     h0p);
                PKFMA_WBV(iBe, wi2[j],     h0p);
                PKFMA_WAV(iAo, wi2[j + 1], h1p);
                PKFMA_WBV(iBo, wi2[j + 1], h1p);
            }
            const v2f pA = iAe + iAo, pB = iBe + iBo;
            v4f pr; pr.x = pA.x; pr.y = pA.y; pr.z = pB.x; pr.w = pB.y;
            pring[t & (RSLOT - 1)][lane] = pr;           // publish partial(t)
            if ((t & (CHUNK - 1)) == (CHUNK - 1) && lane == 0) {
                __hip_atomic_store(&f12, t, __ATOMIC_RELEASE,
                                   __HIP_MEMORY_SCOPE_WORKGROUP);
                __hip_atomic_store(&c10, t, __ATOMIC_RELEASE,
                                   __HIP_MEMORY_SCOPE_WORKGROUP);
            }
        }
    } else if (wave == 2) {
        // ================= stage 2: W_hh2 + gates2 + fc (2 chains) ==========
        v2f wh2[30];
#pragma unroll
        for (int j = 0; j < 30; ++j) {
            wh2[j].x = w_hh2[rowA * HID + j];  wh2[j].y = w_hh2[rowB * HID + j];
        }
#pragma unroll
        for (int j = 0; j < 30; ++j) pinf2(wh2[j]);
        float wfck = (h && k < HID) ? w_fc[k] : 0.0f;
        pinf(wfck);
        const float bfc = __int_as_float(
            __builtin_amdgcn_readfirstlane(__float_as_int(b_fc[0])));
        v2f c2 = z2, hh2 = z2;
        v2f hAe = z2, hAo = z2, hBe = z2, hBo = z2;  // carried W_hh2 . h2(t-1)
        float* outp0 = out + (size_t)b0 * TSTEPS;
        float* outp1 = out + (size_t)b1 * TSTEPS;

        // prologue: wait for chunk 0, prefetch partial(0)
        while (__hip_atomic_load(&f12, __ATOMIC_ACQUIRE,
                                 __HIP_MEMORY_SCOPE_WORKGROUP) < CHUNK - 1)
            __builtin_amdgcn_s_sleep(1);
        v4f part_c = pring[0][lane];

        for (int t = 0; t < TSTEPS; ++t) {
            // ---------------- layer 2, step t (both chains) ----------------
            v2f partA, partB;
            partA.x = part_c.x; partA.y = part_c.y;
            partB.x = part_c.z; partB.y = part_c.w;
            const v2f preA = (hAe + hAo) + partA;
            const v2f preB = (hBe + hBo) + partB;
            v2f gx, gy;
            gx.x = frcp(1.0f + fexp2(preA.x * (-L2E)));
            gx.y = frcp(1.0f + fexp2(preA.y * (-L2E)));
            gy.x = fmaf(frcp(1.0f + fexp2(preB.x * cy)), my, ay);
            gy.y = fmaf(frcp(1.0f + fexp2(preB.y * cy)), my, ay);
            v2f p = gx * gy;
            v2f px;
            px.x = other_half(p.x, h);
            px.y = other_half(p.y, h);
            c2 = gx * c2 + px;
            v2f tc;
            tc.x = fmaf(2.0f, frcp(1.0f + fexp2(c2.x * (-2.0f * L2E))), -1.0f);
            tc.y = fmaf(2.0f, frcp(1.0f + fexp2(c2.y * (-2.0f * L2E))), -1.0f);
            hh2 = gy * tc;              // h2(t)[kk] {b0,b1}, valid in h=1
            const int hlo = __float_as_int(hh2.x), hhi = __float_as_int(hh2.y);

            // prefetch partial(t+1) -- hidden under the broadcast loop below
            v4f part_n = part_c;
            if (t + 1 < TSTEPS) {
                const int tn = t + 1;
                if ((tn & (CHUNK - 1)) == 0) {
                    while (__hip_atomic_load(&f12, __ATOMIC_ACQUIRE,
                                             __HIP_MEMORY_SCOPE_WORKGROUP) < tn + CHUNK - 1)
                        __builtin_amdgcn_s_sleep(1);
                }
                part_n = pring[tn & (RSLOT - 1)][lane];
            }

            // ---- broadcast h2(t) -> carried W_hh2 partial for t+1 ----
            hAe = z2; hAo = z2; hBe = z2; hBo = z2;
#pragma unroll
            for (int j = 0; j < 30; j += 2) {
                const u64 hj  = pk2(__builtin_amdgcn_readlane(hlo, 32 + j),
                                    __builtin_amdgcn_readlane(hhi, 32 + j));
                const u64 hj1 = pk2(__builtin_amdgcn_readlane(hlo, 33 + j),
                                    __builtin_amdgcn_readlane(hhi, 33 + j));
                PKFMA_WA(hAe, wh2[j],     hj);
                PKFMA_WB(hBe, wh2[j],     hj);
                PKFMA_WA(hAo, wh2[j + 1], hj1);
                PKFMA_WB(hBo, wh2[j + 1], hj1);
            }

            // ---------------- fc head (2 chains) ----------------
            const float s0 = dpp_reduce63(wfck * hh2.x);
            const float s1 = dpp_reduce63(wfck * hh2.y);
            if (lane == 63) {
                outp0[t] = s0 + bfc;    // stores stay in flight
                outp1[t] = s1 + bfc;
            }

            if ((t & (CHUNK - 1)) == (CHUNK - 1) && lane == 0)
                __hip_atomic_store(&c21, t, __ATOMIC_RELEASE,
                                   __HIP_MEMORY_SCOPE_WORKGROUP);
            part_c = part_n;
        }
    }
}

extern "C" void kernel_launch(void* const* d_in, const int* in_sizes, int n_in,
                              void* d_out, int out_size, void* d_ws, size_t ws_size,
                              hipStream_t stream)
{
    const float* x     = (const float*)d_in[0];
    const float* w_ih1 = (const float*)d_in[1];
    const float* w_hh1 = (const float*)d_in[2];
    const float* b_ih1 = (const float*)d_in[3];
    const float* b_hh1 = (const float*)d_in[4];
    const float* w_ih2 = (const float*)d_in[5];
    const float* w_hh2 = (const float*)d_in[6];
    const float* b_ih2 = (const float*)d_in[7];
    const float* b_hh2 = (const float*)d_in[8];
    const float* w_fc  = (const float*)d_in[9];
    const float* b_fc  = (const float*)d_in[10];
    float* out = (float*)d_out;

    lstm2_kernel<<<BATCH / 2, 192, 0, stream>>>(x, w_ih1, w_hh1, b_ih1, b_hh1,
                                                w_ih2, w_hh2, b_ih2, b_hh2,
                                                w_fc, b_fc, out);
}

// Round 7
// 1127.242 us; speedup vs baseline: 1.1409x; 1.1409x over previous
//
#include <hip/hip_runtime.h>

typedef float v2f __attribute__((ext_vector_type(2)));
typedef float v4f __attribute__((ext_vector_type(4)));

#define HID 30
#define TSTEPS 2048
#define BATCH 512
#define L2E 1.4426950408889634f
#define RSLOT 64    // ring depth in steps
#define CHUNK 16    // flag granularity in steps

__device__ __forceinline__ float fexp2(float x) { return __builtin_amdgcn_exp2f(x); }
__device__ __forceinline__ float frcp(float x)  { return __builtin_amdgcn_rcpf(x); }
__device__ __forceinline__ void  pinf(float& v) { asm("" : "+v"(v)); }
__device__ __forceinline__ void  pinf2(v2f& v)  { asm("" : "+v"(v)); }

// VALU-free-of-SGPR broadcast: ds_bpermute with uniform byte-address pulls
// lane (addr>>2)'s value into ALL lanes, result lands in a VGPR. Replaces the
// v_readlane -> SGPR-pack -> v_pk_fma(s64) complex that every 1140cy/step
// variant (R0/R2/R4/R5/R6) shared — VALU-write-SGPR/VALU-read hazards plus
// serial SALU packs were the prime suspect for the ~2.5x gap between the
// issue model (~350cy) and the measured step time (1140cy).
__device__ __forceinline__ float bcast(int v, int lane) {
    return __int_as_float(__builtin_amdgcn_ds_bpermute(lane * 4, v));
}

// packed FMA, h operand = VGPR pair {h_j, h_j+1} (R5-wave1-proven macros).
//   VLO: acc{A,B} += w{A,B} * hv.x   (h_j)
//   VHI: acc{A,B} += w{A,B} * hv.y   (h_j+1)
#define PKFMA_VLO(acc, w, hv)                                                \
    asm("v_pk_fma_f32 %0, %1, %2, %0 op_sel:[0,0,0] op_sel_hi:[1,0,1]"       \
        : "+v"(acc) : "v"(w), "v"(hv))
#define PKFMA_VHI(acc, w, hv)                                                \
    asm("v_pk_fma_f32 %0, %1, %2, %0 op_sel:[0,1,0] op_sel_hi:[1,1,1]"       \
        : "+v"(acc) : "v"(w), "v"(hv))

// p from the other 32-lane half (lane ^ 32) via gfx950 VALU permlane32_swap.
__device__ __forceinline__ float other_half(float p, int h) {
#if __has_builtin(__builtin_amdgcn_permlane32_swap)
    auto r = __builtin_amdgcn_permlane32_swap(__float_as_uint(p), __float_as_uint(p),
                                              false, false);
    return __uint_as_float(h ? r[0] : r[1]);
#else
    return __shfl_xor(p, 32);
#endif
}

// Wave-wide sum via DPP (VALU pipe). Valid in lane 63.
__device__ __forceinline__ float dpp_reduce63(float x) {
    x += __int_as_float(__builtin_amdgcn_update_dpp(0, __float_as_int(x), 0x111, 0xf, 0xf, true));
    x += __int_as_float(__builtin_amdgcn_update_dpp(0, __float_as_int(x), 0x112, 0xf, 0xf, true));
    x += __int_as_float(__builtin_amdgcn_update_dpp(0, __float_as_int(x), 0x114, 0xf, 0xf, true));
    x += __int_as_float(__builtin_amdgcn_update_dpp(0, __float_as_int(x), 0x118, 0xf, 0xf, true));
    x += __int_as_float(__builtin_amdgcn_update_dpp(0, __float_as_int(x), 0x142, 0xf, 0xf, true));
    x += __int_as_float(__builtin_amdgcn_update_dpp(0, __float_as_int(x), 0x143, 0xf, 0xf, true));
    return x;
}

// DECOUPLED 3-WAVE CHAIN (R5 structure verbatim, 975us champion), ONE change:
// all self-recurrence broadcasts go through ds_bpermute (VGPR) instead of
// v_readlane (SGPR). Accumulation order bit-identical to R5.
__global__ __launch_bounds__(192, 1)
void lstm2_kernel(const float* __restrict__ x,
                  const float* __restrict__ w_ih1, const float* __restrict__ w_hh1,
                  const float* __restrict__ b_ih1, const float* __restrict__ b_hh1,
                  const float* __restrict__ w_ih2, const float* __restrict__ w_hh2,
                  const float* __restrict__ b_ih2, const float* __restrict__ b_hh2,
                  const float* __restrict__ w_fc,  const float* __restrict__ b_fc,
                  float* __restrict__ out)
{
    const int b    = blockIdx.x;
    const int tid  = threadIdx.x;
    const int wave = tid >> 6;
    const int lane = tid & 63;
    const int k    = lane & 31;
    const int h    = lane >> 5;
    const int kk   = (k < HID) ? k : (HID - 1);  // lanes k=30,31 duplicate unit 29
    const int rowA = h * 30 + kk;                // h0: i-row, h1: f-row
    const int rowB = 60 + h * 30 + kk;           // h0: g-row, h1: o-row

    __shared__ __align__(16) float h1ring[RSLOT][32];  // h1(t) (30 used)
    __shared__ __align__(16) v2f   pring[RSLOT][64];   // {preA,preB} partials
    __shared__ int f01, f12, c10, c21;
    if (tid == 0) { f01 = -1; f12 = -1; c10 = -1; c21 = -1; }
    __syncthreads();                  // only barrier in the kernel

    // gate-y activation constants: h0 -> tanh (g), h1 -> sigmoid (o)
    const float cy = h ? (-L2E) : (-2.0f * L2E);
    const float my = h ? 1.0f : 2.0f;
    const float ay = h ? 0.0f : -1.0f;

    if (wave == 0) {
        // ================= stage 0: layer1 recurrence =================
        v2f w1[30];
#pragma unroll
        for (int j = 0; j < 30; ++j) {
            w1[j].x = w_hh1[rowA * HID + j];  w1[j].y = w_hh1[rowB * HID + j];
        }
        v2f b1AB, z2;
        b1AB.x = b_ih1[rowA] + b_hh1[rowA];  b1AB.y = b_ih1[rowB] + b_hh1[rowB];
        z2.x = 0.0f; z2.y = 0.0f;
        float wxa = w_ih1[rowA];
        float wxb = w_ih1[rowB];
#pragma unroll
        for (int j = 0; j < 30; ++j) pinf2(w1[j]);
        pinf(wxa); pinf(wxb);

        float c1 = 0.0f;
        v2f aABe = b1AB, aABo = z2;     // carried b1 + W_hh1 . h1(t-1)
        const float* xp = x + (size_t)b * TSTEPS;
        float xv_cur = xp[lane];
        float xv_nxt = xp[64 + lane];

        for (int t = 0; t < TSTEPS; ++t) {
            if ((t & (CHUNK - 1)) == 0 && t >= RSLOT) {
                // h1-ring back-pressure
                while (__hip_atomic_load(&c10, __ATOMIC_ACQUIRE,
                                         __HIP_MEMORY_SCOPE_WORKGROUP) < t - (RSLOT - CHUNK + 1))
                    __builtin_amdgcn_s_sleep(1);
            }
            // ---------------- layer 1, step t ----------------
            const float xt = __int_as_float(
                __builtin_amdgcn_readlane(__float_as_int(xv_cur), t & 63));
            v2f pre1 = aABe + aABo;
            pre1.x = fmaf(xt, wxa, pre1.x);
            pre1.y = fmaf(xt, wxb, pre1.y);
            const float gx1 = frcp(1.0f + fexp2(pre1.x * (-L2E)));           // i / f
            const float gy1 = fmaf(frcp(1.0f + fexp2(pre1.y * cy)), my, ay); // g / o
            const float p1  = gx1 * gy1;
            const float px1 = other_half(p1, h);
            c1 = fmaf(gx1, c1, px1);
            const float tc1 = fmaf(2.0f, frcp(1.0f + fexp2(c1 * (-2.0f * L2E))), -1.0f);
            const float hh1 = gy1 * tc1;          // h1(t)[kk], valid in h=1 half
            const int   h1i = __float_as_int(hh1);

            // ---- broadcast h1(t) -> carried W_hh1 partial for t+1 ----
            // 30 independent ds_bpermutes pipeline on the LDS pipe; FMAs use
            // VGPR operands (zero SGPR hazards). Order identical to R5.
            aABe = b1AB; aABo = z2;
#pragma unroll
            for (int j = 0; j < 30; j += 2) {
                v2f hv;
                hv.x = bcast(h1i, 32 + j);
                hv.y = bcast(h1i, 33 + j);
                PKFMA_VLO(aABe, w1[j],     hv);
                PKFMA_VHI(aABo, w1[j + 1], hv);
            }

            if (h) h1ring[t & (RSLOT - 1)][kk] = hh1;   // publish h1(t)
            if ((t & (CHUNK - 1)) == (CHUNK - 1) && lane == 0)
                __hip_atomic_store(&f01, t, __ATOMIC_RELEASE,
                                   __HIP_MEMORY_SCOPE_WORKGROUP);

            if ((t & 63) == 63) {                       // x chunk rotate
                xv_cur = xv_nxt;
                if (t + 65 < TSTEPS) xv_nxt = xp[t + 65 + lane];
            }
        }
    } else if (wave == 1) {
        // ================= stage 1: W_ih2 * h1 + b2 =================
        v2f wi2[30];
#pragma unroll
        for (int j = 0; j < 30; ++j) {
            wi2[j].x = w_ih2[rowA * HID + j];  wi2[j].y = w_ih2[rowB * HID + j];
        }
        v2f b2AB, z2;
        b2AB.x = b_ih2[rowA] + b_hh2[rowA];  b2AB.y = b_ih2[rowB] + b_hh2[rowB];
        z2.x = 0.0f; z2.y = 0.0f;
#pragma unroll
        for (int j = 0; j < 30; ++j) pinf2(wi2[j]);

        for (int t = 0; t < TSTEPS; ++t) {
            if ((t & (CHUNK - 1)) == 0) {
                if (t >= RSLOT) {   // partial-ring back-pressure
                    while (__hip_atomic_load(&c21, __ATOMIC_ACQUIRE,
                                             __HIP_MEMORY_SCOPE_WORKGROUP) < t - (RSLOT - CHUNK + 1))
                        __builtin_amdgcn_s_sleep(1);
                }
                // h1 availability for this chunk
                while (__hip_atomic_load(&f01, __ATOMIC_ACQUIRE,
                                         __HIP_MEMORY_SCOPE_WORKGROUP) < t + CHUNK - 1)
                    __builtin_amdgcn_s_sleep(1);
            }
            // broadcast-read h1(t) (uniform address -> LDS broadcast, no conflict)
            const v4f* rd = (const v4f*)h1ring[t & (RSLOT - 1)];
            v2f i2e = b2AB, i2o = z2;
#pragma unroll
            for (int c = 0; c < 7; ++c) {
                const v4f hc = rd[c];
                v2f p01, p23;
                p01.x = hc.x; p01.y = hc.y;
                p23.x = hc.z; p23.y = hc.w;
                PKFMA_VLO(i2e, wi2[4 * c + 0], p01);
                PKFMA_VHI(i2o, wi2[4 * c + 1], p01);
                PKFMA_VLO(i2e, wi2[4 * c + 2], p23);
                PKFMA_VHI(i2o, wi2[4 * c + 3], p23);
            }
            const v2f tl = ((const v2f*)h1ring[t & (RSLOT - 1)])[14];  // j=28,29
            PKFMA_VLO(i2e, wi2[28], tl);
            PKFMA_VHI(i2o, wi2[29], tl);

            pring[t & (RSLOT - 1)][lane] = i2e + i2o;   // publish partial(t)
            if ((t & (CHUNK - 1)) == (CHUNK - 1) && lane == 0) {
                __hip_atomic_store(&f12, t, __ATOMIC_RELEASE,
                                   __HIP_MEMORY_SCOPE_WORKGROUP);
                __hip_atomic_store(&c10, t, __ATOMIC_RELEASE,
                                   __HIP_MEMORY_SCOPE_WORKGROUP);
            }
        }
    } else if (wave == 2) {
        // ================= stage 2: W_hh2 + gates2 + fc =================
        v2f wh2[30];
#pragma unroll
        for (int j = 0; j < 30; ++j) {
            wh2[j].x = w_hh2[rowA * HID + j];  wh2[j].y = w_hh2[rowB * HID + j];
        }
        v2f z2; z2.x = 0.0f; z2.y = 0.0f;
#pragma unroll
        for (int j = 0; j < 30; ++j) pinf2(wh2[j]);
        float wfck = (h && k < HID) ? w_fc[k] : 0.0f;
        pinf(wfck);
        const float bfc = __int_as_float(
            __builtin_amdgcn_readfirstlane(__float_as_int(b_fc[0])));
        float c2 = 0.0f;
        v2f hABe = z2, hABo = z2;       // carried W_hh2 . h2(t-1)
        float* outp = out + (size_t)b * TSTEPS;

        // prologue: wait for chunk 0, prefetch partial(0)
        while (__hip_atomic_load(&f12, __ATOMIC_ACQUIRE,
                                 __HIP_MEMORY_SCOPE_WORKGROUP) < CHUNK - 1)
            __builtin_amdgcn_s_sleep(1);
        v2f part_c = pring[0][lane];

        for (int t = 0; t < TSTEPS; ++t) {
            // ---------------- layer 2, step t ----------------
            const v2f pre2 = (hABe + hABo) + part_c;
            const float gx2 = frcp(1.0f + fexp2(pre2.x * (-L2E)));
            const float gy2 = fmaf(frcp(1.0f + fexp2(pre2.y * cy)), my, ay);
            const float p2  = gx2 * gy2;
            const float px2 = other_half(p2, h);
            c2 = fmaf(gx2, c2, px2);
            const float tc2 = fmaf(2.0f, frcp(1.0f + fexp2(c2 * (-2.0f * L2E))), -1.0f);
            const float hh2 = gy2 * tc2;          // h2(t)[kk], valid in h=1 half
            const int   h2i = __float_as_int(hh2);

            // prefetch partial(t+1) -- hidden under the broadcast loop below
            v2f part_n = part_c;
            if (t + 1 < TSTEPS) {
                const int tn = t + 1;
                if ((tn & (CHUNK - 1)) == 0) {
                    while (__hip_atomic_load(&f12, __ATOMIC_ACQUIRE,
                                             __HIP_MEMORY_SCOPE_WORKGROUP) < tn + CHUNK - 1)
                        __builtin_amdgcn_s_sleep(1);
                }
                part_n = pring[tn & (RSLOT - 1)][lane];
            }

            // ---- broadcast h2(t) -> carried W_hh2 partial for t+1 ----
            hABe = z2; hABo = z2;
#pragma unroll
            for (int j = 0; j < 30; j += 2) {
                v2f hv;
                hv.x = bcast(h2i, 32 + j);
                hv.y = bcast(h2i, 33 + j);
                PKFMA_VLO(hABe, wh2[j],     hv);
                PKFMA_VHI(hABo, wh2[j + 1], hv);
            }

            // ---------------- fc head ----------------
            const float s = dpp_reduce63(wfck * hh2);
            if (lane == 63) outp[t] = s + bfc;     // store stays in flight

            if ((t & (CHUNK - 1)) == (CHUNK - 1) && lane == 0)
                __hip_atomic_store(&c21, t, __ATOMIC_RELEASE,
                                   __HIP_MEMORY_SCOPE_WORKGROUP);
            part_c = part_n;
        }
    }
}

extern "C" void kernel_launch(void* const* d_in, const int* in_sizes, int n_in,
                              void* d_out, int out_size, void* d_ws, size_t ws_size,
                              hipStream_t stream)
{
    const float* x     = (const float*)d_in[0];
    const float* w_ih1 = (const float*)d_in[1];
    const float* w_hh1 = (const float*)d_in[2];
    const float* b_ih1 = (const float*)d_in[3];
    const float* b_hh1 = (const float*)d_in[4];
    const float* w_ih2 = (const float*)d_in[5];
    const float* w_hh2 = (const float*)d_in[6];
    const float* b_ih2 = (const float*)d_in[7];
    const float* b_hh2 = (const float*)d_in[8];
    const float* w_fc  = (const float*)d_in[9];
    const float* b_fc  = (const float*)d_in[10];
    float* out = (float*)d_out;

    lstm2_kernel<<<BATCH, 192, 0, stream>>>(x, w_ih1, w_hh1, b_ih1, b_hh1,
                                            w_ih2, w_hh2, b_ih2, b_hh2,
                                            w_fc, b_fc, out);
}

// Round 8
// 989.690 us; speedup vs baseline: 1.2995x; 1.1390x over previous
//
#include <hip/hip_runtime.h>

typedef float v2f __attribute__((ext_vector_type(2)));
typedef float v4f __attribute__((ext_vector_type(4)));
typedef unsigned long long u64;

#define HID 30
#define TSTEPS 2048
#define BATCH 512
#define L2E 1.4426950408889634f
#define RSLOT 64    // ring depth in steps
#define CHUNK 16    // flag granularity in steps

__device__ __forceinline__ float fexp2(float x) { return __builtin_amdgcn_exp2f(x); }
__device__ __forceinline__ float frcp(float x)  { return __builtin_amdgcn_rcpf(x); }
__device__ __forceinline__ void  pinf(float& v) { asm("" : "+v"(v)); }
__device__ __forceinline__ void  pinf2(v2f& v)  { asm("" : "+v"(v)); }

__device__ __forceinline__ u64 pk2(int lo, int hi) {
    return ((u64)(unsigned)hi << 32) | (unsigned)lo;
}

// packed FMA, src1 = SGPR pair (R2/R4/R5-proven semantics).
//   LO: acc{A,B} += w{A,B} * s64.lo ;  HI: acc{A,B} += w{A,B} * s64.hi
#define PKFMA_LO(acc, w, s64)                                                \
    asm("v_pk_fma_f32 %0, %1, %2, %0 op_sel:[0,0,0] op_sel_hi:[1,0,1]"       \
        : "+v"(acc) : "v"(w), "s"(s64))
#define PKFMA_HI(acc, w, s64)                                                \
    asm("v_pk_fma_f32 %0, %1, %2, %0 op_sel:[0,1,0] op_sel_hi:[1,1,1]"       \
        : "+v"(acc) : "v"(w), "s"(s64))
// VGPR-pair h variants (LDS-loaded values, wave1)
#define PKFMA_VLO(acc, w, hv)                                                \
    asm("v_pk_fma_f32 %0, %1, %2, %0 op_sel:[0,0,0] op_sel_hi:[1,0,1]"       \
        : "+v"(acc) : "v"(w), "v"(hv))
#define PKFMA_VHI(acc, w, hv)                                                \
    asm("v_pk_fma_f32 %0, %1, %2, %0 op_sel:[0,1,0] op_sel_hi:[1,1,1]"       \
        : "+v"(acc) : "v"(w), "v"(hv))

// p from the other 32-lane half (lane ^ 32) via gfx950 VALU permlane32_swap.
__device__ __forceinline__ float other_half(float p, int h) {
#if __has_builtin(__builtin_amdgcn_permlane32_swap)
    auto r = __builtin_amdgcn_permlane32_swap(__float_as_uint(p), __float_as_uint(p),
                                              false, false);
    return __uint_as_float(h ? r[0] : r[1]);
#else
    return __shfl_xor(p, 32);
#endif
}

// Wave-wide sum via DPP (VALU pipe). Valid in lane 63.
__device__ __forceinline__ float dpp_reduce63(float x) {
    x += __int_as_float(__builtin_amdgcn_update_dpp(0, __float_as_int(x), 0x111, 0xf, 0xf, true));
    x += __int_as_float(__builtin_amdgcn_update_dpp(0, __float_as_int(x), 0x112, 0xf, 0xf, true));
    x += __int_as_float(__builtin_amdgcn_update_dpp(0, __float_as_int(x), 0x114, 0xf, 0xf, true));
    x += __int_as_float(__builtin_amdgcn_update_dpp(0, __float_as_int(x), 0x118, 0xf, 0xf, true));
    x += __int_as_float(__builtin_amdgcn_update_dpp(0, __float_as_int(x), 0x142, 0xf, 0xf, true));
    x += __int_as_float(__builtin_amdgcn_update_dpp(0, __float_as_int(x), 0x143, 0xf, 0xf, true));
    return x;
}

// R5 STRUCTURE (975us champion), scheduling-only changes:
//  (a) ALL readlanes batched BEFORE all pk_fmas (VALU->SGPR->VALU hazard
//      windows filled by independent readlane issues instead of wait-states;
//      R7 proved the broadcast mechanism itself wasn't the problem — bpermute
//      regressed — so the remaining suspect is readlane/FMA interleaving)
//  (b) xt prefetched one step ahead (hazard off the step-opening chain)
//  (c) h1 published immediately after computation (wave1 starts earlier)
// Numerics bit-identical to R5.
__global__ __launch_bounds__(192, 1)
void lstm2_kernel(const float* __restrict__ x,
                  const float* __restrict__ w_ih1, const float* __restrict__ w_hh1,
                  const float* __restrict__ b_ih1, const float* __restrict__ b_hh1,
                  const float* __restrict__ w_ih2, const float* __restrict__ w_hh2,
                  const float* __restrict__ b_ih2, const float* __restrict__ b_hh2,
                  const float* __restrict__ w_fc,  const float* __restrict__ b_fc,
                  float* __restrict__ out)
{
    const int b    = blockIdx.x;
    const int tid  = threadIdx.x;
    const int wave = tid >> 6;
    const int lane = tid & 63;
    const int k    = lane & 31;
    const int h    = lane >> 5;
    const int kk   = (k < HID) ? k : (HID - 1);  // lanes k=30,31 duplicate unit 29
    const int rowA = h * 30 + kk;                // h0: i-row, h1: f-row
    const int rowB = 60 + h * 30 + kk;           // h0: g-row, h1: o-row

    __shared__ __align__(16) float h1ring[RSLOT][32];  // h1(t) (30 used)
    __shared__ __align__(16) v2f   pring[RSLOT][64];   // {preA,preB} partials
    __shared__ int f01, f12, c10, c21;
    if (tid == 0) { f01 = -1; f12 = -1; c10 = -1; c21 = -1; }
    __syncthreads();                  // only barrier in the kernel

    // gate-y activation constants: h0 -> tanh (g), h1 -> sigmoid (o)
    const float cy = h ? (-L2E) : (-2.0f * L2E);
    const float my = h ? 1.0f : 2.0f;
    const float ay = h ? 0.0f : -1.0f;

    if (wave == 0) {
        // ================= stage 0: layer1 recurrence =================
        v2f w1[30];
#pragma unroll
        for (int j = 0; j < 30; ++j) {
            w1[j].x = w_hh1[rowA * HID + j];  w1[j].y = w_hh1[rowB * HID + j];
        }
        v2f b1AB, z2;
        b1AB.x = b_ih1[rowA] + b_hh1[rowA];  b1AB.y = b_ih1[rowB] + b_hh1[rowB];
        z2.x = 0.0f; z2.y = 0.0f;
        float wxa = w_ih1[rowA];
        float wxb = w_ih1[rowB];
#pragma unroll
        for (int j = 0; j < 30; ++j) pinf2(w1[j]);
        pinf(wxa); pinf(wxb);

        float c1 = 0.0f;
        v2f aABe = b1AB, aABo = z2;     // carried b1 + W_hh1 . h1(t-1)
        const float* xp = x + (size_t)b * TSTEPS;
        float xv_cur = xp[lane];
        float xv_nxt = xp[64 + lane];
        // xt prefetched one step ahead: hazard distance >> 1 instr
        float xt_c = __int_as_float(
            __builtin_amdgcn_readlane(__float_as_int(xv_cur), 0));

        for (int t = 0; t < TSTEPS; ++t) {
            if ((t & (CHUNK - 1)) == 0 && t >= RSLOT) {
                // h1-ring back-pressure
                while (__hip_atomic_load(&c10, __ATOMIC_ACQUIRE,
                                         __HIP_MEMORY_SCOPE_WORKGROUP) < t - (RSLOT - CHUNK + 1))
                    __builtin_amdgcn_s_sleep(1);
            }
            // ---------------- layer 1, step t ----------------
            v2f pre1 = aABe + aABo;
            pre1.x = fmaf(xt_c, wxa, pre1.x);
            pre1.y = fmaf(xt_c, wxb, pre1.y);
            const float gx1 = frcp(1.0f + fexp2(pre1.x * (-L2E)));           // i / f
            const float gy1 = fmaf(frcp(1.0f + fexp2(pre1.y * cy)), my, ay); // g / o
            const float p1  = gx1 * gy1;
            const float px1 = other_half(p1, h);
            c1 = fmaf(gx1, c1, px1);
            const float tc1 = fmaf(2.0f, frcp(1.0f + fexp2(c1 * (-2.0f * L2E))), -1.0f);
            const float hh1 = gy1 * tc1;          // h1(t)[kk], valid in h=1 half
            const int   h1i = __float_as_int(hh1);

            // publish h1(t) NOW (DS ops in-order per wave -> release flag at
            // chunk end still orders it); wave1 can start ~300cy earlier
            if (h) h1ring[t & (RSLOT - 1)][kk] = hh1;

            // ---- broadcast h1(t): ALL readlanes first, THEN all FMAs ----
            u64 hb[15];
#pragma unroll
            for (int j = 0; j < 15; ++j)
                hb[j] = pk2(__builtin_amdgcn_readlane(h1i, 32 + 2 * j),
                            __builtin_amdgcn_readlane(h1i, 33 + 2 * j));
            aABe = b1AB; aABo = z2;
#pragma unroll
            for (int j = 0; j < 15; ++j) {
                PKFMA_LO(aABe, w1[2 * j],     hb[j]);
                PKFMA_HI(aABo, w1[2 * j + 1], hb[j]);
            }

            if ((t & (CHUNK - 1)) == (CHUNK - 1) && lane == 0)
                __hip_atomic_store(&f01, t, __ATOMIC_RELEASE,
                                   __HIP_MEMORY_SCOPE_WORKGROUP);

            if ((t & 63) == 63) {                       // x chunk rotate
                xv_cur = xv_nxt;
                if (t + 65 < TSTEPS) xv_nxt = xp[t + 65 + lane];
            }
            xt_c = __int_as_float(
                __builtin_amdgcn_readlane(__float_as_int(xv_cur), (t + 1) & 63));
        }
    } else if (wave == 1) {
        // ================= stage 1: W_ih2 * h1 + b2 =================
        v2f wi2[30];
#pragma unroll
        for (int j = 0; j < 30; ++j) {
            wi2[j].x = w_ih2[rowA * HID + j];  wi2[j].y = w_ih2[rowB * HID + j];
        }
        v2f b2AB, z2;
        b2AB.x = b_ih2[rowA] + b_hh2[rowA];  b2AB.y = b_ih2[rowB] + b_hh2[rowB];
        z2.x = 0.0f; z2.y = 0.0f;
#pragma unroll
        for (int j = 0; j < 30; ++j) pinf2(wi2[j]);

        for (int t = 0; t < TSTEPS; ++t) {
            if ((t & (CHUNK - 1)) == 0) {
                if (t >= RSLOT) {   // partial-ring back-pressure
                    while (__hip_atomic_load(&c21, __ATOMIC_ACQUIRE,
                                             __HIP_MEMORY_SCOPE_WORKGROUP) < t - (RSLOT - CHUNK + 1))
                        __builtin_amdgcn_s_sleep(1);
                }
                // h1 availability for this chunk
                while (__hip_atomic_load(&f01, __ATOMIC_ACQUIRE,
                                         __HIP_MEMORY_SCOPE_WORKGROUP) < t + CHUNK - 1)
                    __builtin_amdgcn_s_sleep(1);
            }
            // broadcast-read h1(t) (uniform address -> LDS broadcast, no conflict)
            const v4f* rd = (const v4f*)h1ring[t & (RSLOT - 1)];
            v2f i2e = b2AB, i2o = z2;
#pragma unroll
            for (int c = 0; c < 7; ++c) {
                const v4f hc = rd[c];
                v2f p01, p23;
                p01.x = hc.x; p01.y = hc.y;
                p23.x = hc.z; p23.y = hc.w;
                PKFMA_VLO(i2e, wi2[4 * c + 0], p01);
                PKFMA_VHI(i2o, wi2[4 * c + 1], p01);
                PKFMA_VLO(i2e, wi2[4 * c + 2], p23);
                PKFMA_VHI(i2o, wi2[4 * c + 3], p23);
            }
            const v2f tl = ((const v2f*)h1ring[t & (RSLOT - 1)])[14];  // j=28,29
            PKFMA_VLO(i2e, wi2[28], tl);
            PKFMA_VHI(i2o, wi2[29], tl);

            pring[t & (RSLOT - 1)][lane] = i2e + i2o;   // publish partial(t)
            if ((t & (CHUNK - 1)) == (CHUNK - 1) && lane == 0) {
                __hip_atomic_store(&f12, t, __ATOMIC_RELEASE,
                                   __HIP_MEMORY_SCOPE_WORKGROUP);
                __hip_atomic_store(&c10, t, __ATOMIC_RELEASE,
                                   __HIP_MEMORY_SCOPE_WORKGROUP);
            }
        }
    } else if (wave == 2) {
        // ================= stage 2: W_hh2 + gates2 + fc =================
        v2f wh2[30];
#pragma unroll
        for (int j = 0; j < 30; ++j) {
            wh2[j].x = w_hh2[rowA * HID + j];  wh2[j].y = w_hh2[rowB * HID + j];
        }
        v2f z2; z2.x = 0.0f; z2.y = 0.0f;
#pragma unroll
        for (int j = 0; j < 30; ++j) pinf2(wh2[j]);
        float wfck = (h && k < HID) ? w_fc[k] : 0.0f;
        pinf(wfck);
        const float bfc = __int_as_float(
            __builtin_amdgcn_readfirstlane(__float_as_int(b_fc[0])));
        float c2 = 0.0f;
        v2f hABe = z2, hABo = z2;       // carried W_hh2 . h2(t-1)
        float* outp = out + (size_t)b * TSTEPS;

        // prologue: wait for chunk 0, prefetch partial(0)
        while (__hip_atomic_load(&f12, __ATOMIC_ACQUIRE,
                                 __HIP_MEMORY_SCOPE_WORKGROUP) < CHUNK - 1)
            __builtin_amdgcn_s_sleep(1);
        v2f part_c = pring[0][lane];

        for (int t = 0; t < TSTEPS; ++t) {
            // ---------------- layer 2, step t ----------------
            const v2f pre2 = (hABe + hABo) + part_c;
            const float gx2 = frcp(1.0f + fexp2(pre2.x * (-L2E)));
            const float gy2 = fmaf(frcp(1.0f + fexp2(pre2.y * cy)), my, ay);
            const float p2  = gx2 * gy2;
            const float px2 = other_half(p2, h);
            c2 = fmaf(gx2, c2, px2);
            const float tc2 = fmaf(2.0f, frcp(1.0f + fexp2(c2 * (-2.0f * L2E))), -1.0f);
            const float hh2 = gy2 * tc2;          // h2(t)[kk], valid in h=1 half
            const int   h2i = __float_as_int(hh2);

            // ---- ALL readlanes first (hazard windows filled), then FMAs ----
            u64 hb[15];
#pragma unroll
            for (int j = 0; j < 15; ++j)
                hb[j] = pk2(__builtin_amdgcn_readlane(h2i, 32 + 2 * j),
                            __builtin_amdgcn_readlane(h2i, 33 + 2 * j));

            // prefetch partial(t+1) -- independent LDS read in the gap
            v2f part_n = part_c;
            if (t + 1 < TSTEPS) {
                const int tn = t + 1;
                if ((tn & (CHUNK - 1)) == 0) {
                    while (__hip_atomic_load(&f12, __ATOMIC_ACQUIRE,
                                             __HIP_MEMORY_SCOPE_WORKGROUP) < tn + CHUNK - 1)
                        __builtin_amdgcn_s_sleep(1);
                }
                part_n = pring[tn & (RSLOT - 1)][lane];
            }

            hABe = z2; hABo = z2;
#pragma unroll
            for (int j = 0; j < 15; ++j) {
                PKFMA_LO(hABe, wh2[2 * j],     hb[j]);
                PKFMA_HI(hABo, wh2[2 * j + 1], hb[j]);
            }

            // ---------------- fc head ----------------
            const float s = dpp_reduce63(wfck * hh2);
            if (lane == 63) outp[t] = s + bfc;     // store stays in flight

            if ((t & (CHUNK - 1)) == (CHUNK - 1) && lane == 0)
                __hip_atomic_store(&c21, t, __ATOMIC_RELEASE,
                                   __HIP_MEMORY_SCOPE_WORKGROUP);
            part_c = part_n;
        }
    }
}

extern "C" void kernel_launch(void* const* d_in, const int* in_sizes, int n_in,
                              void* d_out, int out_size, void* d_ws, size_t ws_size,
                              hipStream_t stream)
{
    const float* x     = (const float*)d_in[0];
    const float* w_ih1 = (const float*)d_in[1];
    const float* w_hh1 = (const float*)d_in[2];
    const float* b_ih1 = (const float*)d_in[3];
    const float* b_hh1 = (const float*)d_in[4];
    const float* w_ih2 = (const float*)d_in[5];
    const float* w_hh2 = (const float*)d_in[6];
    const float* b_ih2 = (const float*)d_in[7];
    const float* b_hh2 = (const float*)d_in[8];
    const float* w_fc  = (const float*)d_in[9];
    const float* b_fc  = (const float*)d_in[10];
    float* out = (float*)d_out;

    lstm2_kernel<<<BATCH, 192, 0, stream>>>(x, w_ih1, w_hh1, b_ih1, b_hh1,
                                            w_ih2, w_hh2, b_ih2, b_hh2,
                                            w_fc, b_fc, out);
}

// Round 9
// 977.982 us; speedup vs baseline: 1.3150x; 1.0120x over previous
//
#include <hip/hip_runtime.h>

typedef float v2f __attribute__((ext_vector_type(2)));
typedef float v4f __attribute__((ext_vector_type(4)));
typedef unsigned long long u64;

#define HID 30
#define TSTEPS 2048
#define BATCH 512
#define L2E 1.4426950408889634f
#define RSLOT 64    // ring depth in steps
#define CHUNK 16    // flag granularity in steps

__device__ __forceinline__ float fexp2(float x) { return __builtin_amdgcn_exp2f(x); }
__device__ __forceinline__ float frcp(float x)  { return __builtin_amdgcn_rcpf(x); }
__device__ __forceinline__ void  pinf(float& v) { asm("" : "+v"(v)); }
__device__ __forceinline__ void  pinf2(v2f& v)  { asm("" : "+v"(v)); }

__device__ __forceinline__ u64 pk2(int lo, int hi) {
    return ((u64)(unsigned)hi << 32) | (unsigned)lo;
}

// packed FMA, src1 = SGPR pair (R2/R4/R5-proven semantics).
#define PKFMA_LO(acc, w, s64)                                                \
    asm("v_pk_fma_f32 %0, %1, %2, %0 op_sel:[0,0,0] op_sel_hi:[1,0,1]"       \
        : "+v"(acc) : "v"(w), "s"(s64))
#define PKFMA_HI(acc, w, s64)                                                \
    asm("v_pk_fma_f32 %0, %1, %2, %0 op_sel:[0,1,0] op_sel_hi:[1,1,1]"       \
        : "+v"(acc) : "v"(w), "s"(s64))
// VGPR-pair h variants (LDS-loaded values, wave1)
#define PKFMA_VLO(acc, w, hv)                                                \
    asm("v_pk_fma_f32 %0, %1, %2, %0 op_sel:[0,0,0] op_sel_hi:[1,0,1]"       \
        : "+v"(acc) : "v"(w), "v"(hv))
#define PKFMA_VHI(acc, w, hv)                                                \
    asm("v_pk_fma_f32 %0, %1, %2, %0 op_sel:[0,1,0] op_sel_hi:[1,1,1]"       \
        : "+v"(acc) : "v"(w), "v"(hv))

// p from the other 32-lane half (lane ^ 32) via gfx950 VALU permlane32_swap.
__device__ __forceinline__ float other_half(float p, int h) {
#if __has_builtin(__builtin_amdgcn_permlane32_swap)
    auto r = __builtin_amdgcn_permlane32_swap(__float_as_uint(p), __float_as_uint(p),
                                              false, false);
    return __uint_as_float(h ? r[0] : r[1]);
#else
    return __shfl_xor(p, 32);
#endif
}

// Wave-wide sum via DPP (VALU pipe). Valid in lane 63.
__device__ __forceinline__ float dpp_reduce63(float x) {
    x += __int_as_float(__builtin_amdgcn_update_dpp(0, __float_as_int(x), 0x111, 0xf, 0xf, true));
    x += __int_as_float(__builtin_amdgcn_update_dpp(0, __float_as_int(x), 0x112, 0xf, 0xf, true));
    x += __int_as_float(__builtin_amdgcn_update_dpp(0, __float_as_int(x), 0x114, 0xf, 0xf, true));
    x += __int_as_float(__builtin_amdgcn_update_dpp(0, __float_as_int(x), 0x118, 0xf, 0xf, true));
    x += __int_as_float(__builtin_amdgcn_update_dpp(0, __float_as_int(x), 0x142, 0xf, 0xf, true));
    x += __int_as_float(__builtin_amdgcn_update_dpp(0, __float_as_int(x), 0x143, 0xf, 0xf, true));
    return x;
}

// R5/R8 FRAME, loop-carried-CHAIN-SHORTENING round (R8 proved scheduling is
// already optimal; R6 decomposition: step = ~793cy chain + ~350cy issue).
//  (1) weights/bias PRE-SCALED by exp2-arg constants; cell state kept in
//      scaled space c' = -2*L2E*c  -> the mul before EVERY exp2 is gone
//  (2) tanh epilogue folded: hh = fma(2*gy, rcp, -gy) (2gy,-gy off-chain)
//  (3) broadcast matvec: 4 accumulators, depth 15 -> 8  (3 pk_adds merge)
//  (4) persistent s_setprio(1) on recurrence waves (0,2)
__global__ __launch_bounds__(192, 1)
void lstm2_kernel(const float* __restrict__ x,
                  const float* __restrict__ w_ih1, const float* __restrict__ w_hh1,
                  const float* __restrict__ b_ih1, const float* __restrict__ b_hh1,
                  const float* __restrict__ w_ih2, const float* __restrict__ w_hh2,
                  const float* __restrict__ b_ih2, const float* __restrict__ b_hh2,
                  const float* __restrict__ w_fc,  const float* __restrict__ b_fc,
                  float* __restrict__ out)
{
    const int b    = blockIdx.x;
    const int tid  = threadIdx.x;
    const int wave = tid >> 6;
    const int lane = tid & 63;
    const int k    = lane & 31;
    const int h    = lane >> 5;
    const int kk   = (k < HID) ? k : (HID - 1);  // lanes k=30,31 duplicate unit 29
    const int rowA = h * 30 + kk;                // h0: i-row, h1: f-row
    const int rowB = 60 + h * 30 + kk;           // h0: g-row, h1: o-row

    __shared__ __align__(16) float h1ring[RSLOT][32];  // h1(t) (30 used)
    __shared__ __align__(16) v2f   pring[RSLOT][64];   // {preA',preB'} scaled partials
    __shared__ int f01, f12, c10, c21;
    if (tid == 0) { f01 = -1; f12 = -1; c10 = -1; c21 = -1; }
    __syncthreads();                  // only barrier in the kernel

    // exp2-argument scales: A rows (i/f, sigmoid) -> -L2E; B rows: h0 g-gate
    // (tanh, arg 2x) -> -2*L2E, h1 o-gate (sigmoid) -> -L2E.
    const float sA = -L2E;
    const float cy = h ? (-L2E) : (-2.0f * L2E);
    // g-gate folded into scaled space: g' = -2L2E*(2r-1) = fma(r,-4L2E,+2L2E);
    // o-gate stays plain sigmoid: fma(r, 1, 0).
    const float my = h ? 1.0f : (-4.0f * L2E);
    const float ay = h ? 0.0f : ( 2.0f * L2E);

    if (wave != 1) __builtin_amdgcn_s_setprio(1);   // recurrence waves win arbitration

    if (wave == 0) {
        // ================= stage 0: layer1 recurrence =================
        v2f w1[30];
#pragma unroll
        for (int j = 0; j < 30; ++j) {
            w1[j].x = sA * w_hh1[rowA * HID + j];  w1[j].y = cy * w_hh1[rowB * HID + j];
        }
        v2f b1AB, z2;
        b1AB.x = sA * (b_ih1[rowA] + b_hh1[rowA]);
        b1AB.y = cy * (b_ih1[rowB] + b_hh1[rowB]);
        z2.x = 0.0f; z2.y = 0.0f;
        float wxa = sA * w_ih1[rowA];
        float wxb = cy * w_ih1[rowB];
#pragma unroll
        for (int j = 0; j < 30; ++j) pinf2(w1[j]);
        pinf(wxa); pinf(wxb);

        float c1 = 0.0f;                // scaled cell state c' = -2L2E*c
        v2f e0 = b1AB, e1 = z2, o0 = z2, o1 = z2;   // 4-way accumulator split
        const float* xp = x + (size_t)b * TSTEPS;
        float xv_cur = xp[lane];
        float xv_nxt = xp[64 + lane];
        float xt_c = __int_as_float(
            __builtin_amdgcn_readlane(__float_as_int(xv_cur), 0));

        for (int t = 0; t < TSTEPS; ++t) {
            if ((t & (CHUNK - 1)) == 0 && t >= RSLOT) {
                while (__hip_atomic_load(&c10, __ATOMIC_ACQUIRE,
                                         __HIP_MEMORY_SCOPE_WORKGROUP) < t - (RSLOT - CHUNK + 1))
                    __builtin_amdgcn_s_sleep(1);
            }
            // ---------------- layer 1, step t (scaled space) ----------------
            v2f pre1 = (e0 + e1) + (o0 + o1);
            pre1.x = fmaf(xt_c, wxa, pre1.x);
            pre1.y = fmaf(xt_c, wxb, pre1.y);
            const float gx1 = frcp(1.0f + fexp2(pre1.x));            // sigma(i/f)
            const float gy1 = fmaf(frcp(1.0f + fexp2(pre1.y)), my, ay); // g' / sigma(o)
            const float g2y = 2.0f * gy1;                            // off-chain
            const float p1  = gx1 * gy1;
            const float px1 = other_half(p1, h);
            c1 = fmaf(gx1, c1, px1);                // c' recurrence (h=1 valid)
            const float r1  = frcp(1.0f + fexp2(c1));
            const float hh1 = fmaf(g2y, r1, -gy1);  // o * tanh(c), h=1 valid
            const int   h1i = __float_as_int(hh1);

            // publish h1(t) immediately (DS in-order; flag still orders it)
            if (h) h1ring[t & (RSLOT - 1)][kk] = hh1;

            // ---- broadcast h1(t): readlanes batched, 4-chain matvec ----
            u64 hb[15];
#pragma unroll
            for (int j = 0; j < 15; ++j)
                hb[j] = pk2(__builtin_amdgcn_readlane(h1i, 32 + 2 * j),
                            __builtin_amdgcn_readlane(h1i, 33 + 2 * j));
            e0 = b1AB; e1 = z2; o0 = z2; o1 = z2;
#pragma unroll
            for (int j = 0; j < 15; j += 2) {       // 8 iters -> depth 8
                PKFMA_LO(e0, w1[2 * j],     hb[j]);
                PKFMA_HI(o0, w1[2 * j + 1], hb[j]);
            }
#pragma unroll
            for (int j = 1; j < 15; j += 2) {       // 7 iters -> depth 7
                PKFMA_LO(e1, w1[2 * j],     hb[j]);
                PKFMA_HI(o1, w1[2 * j + 1], hb[j]);
            }

            if ((t & (CHUNK - 1)) == (CHUNK - 1) && lane == 0)
                __hip_atomic_store(&f01, t, __ATOMIC_RELEASE,
                                   __HIP_MEMORY_SCOPE_WORKGROUP);

            if ((t & 63) == 63) {                   // x chunk rotate
                xv_cur = xv_nxt;
                if (t + 65 < TSTEPS) xv_nxt = xp[t + 65 + lane];
            }
            xt_c = __int_as_float(
                __builtin_amdgcn_readlane(__float_as_int(xv_cur), (t + 1) & 63));
        }
    } else if (wave == 1) {
        // ================= stage 1: W_ih2' * h1 + b2' (scaled) ==============
        v2f wi2[30];
#pragma unroll
        for (int j = 0; j < 30; ++j) {
            wi2[j].x = sA * w_ih2[rowA * HID + j];  wi2[j].y = cy * w_ih2[rowB * HID + j];
        }
        v2f b2AB, z2;
        b2AB.x = sA * (b_ih2[rowA] + b_hh2[rowA]);
        b2AB.y = cy * (b_ih2[rowB] + b_hh2[rowB]);
        z2.x = 0.0f; z2.y = 0.0f;
#pragma unroll
        for (int j = 0; j < 30; ++j) pinf2(wi2[j]);

        for (int t = 0; t < TSTEPS; ++t) {
            if ((t & (CHUNK - 1)) == 0) {
                if (t >= RSLOT) {   // partial-ring back-pressure
                    while (__hip_atomic_load(&c21, __ATOMIC_ACQUIRE,
                                             __HIP_MEMORY_SCOPE_WORKGROUP) < t - (RSLOT - CHUNK + 1))
                        __builtin_amdgcn_s_sleep(1);
                }
                while (__hip_atomic_load(&f01, __ATOMIC_ACQUIRE,
                                         __HIP_MEMORY_SCOPE_WORKGROUP) < t + CHUNK - 1)
                    __builtin_amdgcn_s_sleep(1);
            }
            // broadcast-read h1(t) (uniform address -> LDS broadcast)
            const v4f* rd = (const v4f*)h1ring[t & (RSLOT - 1)];
            v2f i2e = b2AB, i2o = z2;
#pragma unroll
            for (int c = 0; c < 7; ++c) {
                const v4f hc = rd[c];
                v2f p01, p23;
                p01.x = hc.x; p01.y = hc.y;
                p23.x = hc.z; p23.y = hc.w;
                PKFMA_VLO(i2e, wi2[4 * c + 0], p01);
                PKFMA_VHI(i2o, wi2[4 * c + 1], p01);
                PKFMA_VLO(i2e, wi2[4 * c + 2], p23);
                PKFMA_VHI(i2o, wi2[4 * c + 3], p23);
            }
            const v2f tl = ((const v2f*)h1ring[t & (RSLOT - 1)])[14];  // j=28,29
            PKFMA_VLO(i2e, wi2[28], tl);
            PKFMA_VHI(i2o, wi2[29], tl);

            pring[t & (RSLOT - 1)][lane] = i2e + i2o;   // publish scaled partial
            if ((t & (CHUNK - 1)) == (CHUNK - 1) && lane == 0) {
                __hip_atomic_store(&f12, t, __ATOMIC_RELEASE,
                                   __HIP_MEMORY_SCOPE_WORKGROUP);
                __hip_atomic_store(&c10, t, __ATOMIC_RELEASE,
                                   __HIP_MEMORY_SCOPE_WORKGROUP);
            }
        }
    } else if (wave == 2) {
        // ================= stage 2: W_hh2' + gates2 + fc (scaled) ===========
        v2f wh2[30];
#pragma unroll
        for (int j = 0; j < 30; ++j) {
            wh2[j].x = sA * w_hh2[rowA * HID + j];  wh2[j].y = cy * w_hh2[rowB * HID + j];
        }
        v2f z2; z2.x = 0.0f; z2.y = 0.0f;
#pragma unroll
        for (int j = 0; j < 30; ++j) pinf2(wh2[j]);
        float wfck = (h && k < HID) ? w_fc[k] : 0.0f;
        pinf(wfck);
        const float bfc = __int_as_float(
            __builtin_amdgcn_readfirstlane(__float_as_int(b_fc[0])));
        float c2 = 0.0f;                // scaled cell state
        v2f e0 = z2, e1 = z2, o0 = z2, o1 = z2;   // 4-way split (W_hh2 . h2)
        float* outp = out + (size_t)b * TSTEPS;

        // prologue: wait for chunk 0, prefetch partial(0)
        while (__hip_atomic_load(&f12, __ATOMIC_ACQUIRE,
                                 __HIP_MEMORY_SCOPE_WORKGROUP) < CHUNK - 1)
            __builtin_amdgcn_s_sleep(1);
        v2f part_c = pring[0][lane];

        for (int t = 0; t < TSTEPS; ++t) {
            // ---------------- layer 2, step t (scaled space) ----------------
            const v2f pre2 = ((e0 + e1) + (o0 + o1)) + part_c;
            const float gx2 = frcp(1.0f + fexp2(pre2.x));
            const float gy2 = fmaf(frcp(1.0f + fexp2(pre2.y)), my, ay);
            const float g2y = 2.0f * gy2;
            const float p2  = gx2 * gy2;
            const float px2 = other_half(p2, h);
            c2 = fmaf(gx2, c2, px2);
            const float r2  = frcp(1.0f + fexp2(c2));
            const float hh2 = fmaf(g2y, r2, -gy2);  // h2(t)[kk], h=1 valid
            const int   h2i = __float_as_int(hh2);

            // ---- readlanes batched; prefetch partial(t+1) in the gap ----
            u64 hb[15];
#pragma unroll
            for (int j = 0; j < 15; ++j)
                hb[j] = pk2(__builtin_amdgcn_readlane(h2i, 32 + 2 * j),
                            __builtin_amdgcn_readlane(h2i, 33 + 2 * j));

            v2f part_n = part_c;
            if (t + 1 < TSTEPS) {
                const int tn = t + 1;
                if ((tn & (CHUNK - 1)) == 0) {
                    while (__hip_atomic_load(&f12, __ATOMIC_ACQUIRE,
                                             __HIP_MEMORY_SCOPE_WORKGROUP) < tn + CHUNK - 1)
                        __builtin_amdgcn_s_sleep(1);
                }
                part_n = pring[tn & (RSLOT - 1)][lane];
            }

            e0 = z2; e1 = z2; o0 = z2; o1 = z2;
#pragma unroll
            for (int j = 0; j < 15; j += 2) {
                PKFMA_LO(e0, wh2[2 * j],     hb[j]);
                PKFMA_HI(o0, wh2[2 * j + 1], hb[j]);
            }
#pragma unroll
            for (int j = 1; j < 15; j += 2) {
                PKFMA_LO(e1, wh2[2 * j],     hb[j]);
                PKFMA_HI(o1, wh2[2 * j + 1], hb[j]);
            }

            // ---------------- fc head ----------------
            const float s = dpp_reduce63(wfck * hh2);
            if (lane == 63) outp[t] = s + bfc;     // store stays in flight

            if ((t & (CHUNK - 1)) == (CHUNK - 1) && lane == 0)
                __hip_atomic_store(&c21, t, __ATOMIC_RELEASE,
                                   __HIP_MEMORY_SCOPE_WORKGROUP);
            part_c = part_n;
        }
    }
}

extern "C" void kernel_launch(void* const* d_in, const int* in_sizes, int n_in,
                              void* d_out, int out_size, void* d_ws, size_t ws_size,
                              hipStream_t stream)
{
    const float* x     = (const float*)d_in[0];
    const float* w_ih1 = (const float*)d_in[1];
    const float* w_hh1 = (const float*)d_in[2];
    const float* b_ih1 = (const float*)d_in[3];
    const float* b_hh1 = (const float*)d_in[4];
    const float* w_ih2 = (const float*)d_in[5];
    const float* w_hh2 = (const float*)d_in[6];
    const float* b_ih2 = (const float*)d_in[7];
    const float* b_hh2 = (const float*)d_in[8];
    const float* w_fc  = (const float*)d_in[9];
    const float* b_fc  = (const float*)d_in[10];
    float* out = (float*)d_out;

    lstm2_kernel<<<BATCH, 192, 0, stream>>>(x, w_ih1, w_hh1, b_ih1, b_hh1,
                                            w_ih2, w_hh2, b_ih2, b_hh2,
                                            w_fc, b_fc, out);
}